// Round 2
// baseline (6379.887 us; speedup 1.0000x reference)
//
#include <hip/hip_runtime.h>

#define B_ 8
#define N_ 3136
#define C_ 512
#define NH_ 8
#define HD_ 64
#define FF_ 4096
#define M_ (B_*N_)   // 25088
#define CHUNK_ROWS 1792
#define N_CHUNKS 14

// ---- workspace layout (float offsets), total ~230 MB ----
#define OFF_KV   0LL
#define SZ_KV    ((long long)M_*1024)          // [k(transformed) | v] per row; attn overwrites k-half
#define OFF_Q    (OFF_KV + SZ_KV)
#define SZ_Q     ((long long)M_*512)           // qraw = q/scale
#define OFF_G    (OFF_Q + SZ_Q)
#define SZ_G     ((long long)M_*512)           // g
#define OFF_H1   (OFF_G + SZ_G)
#define SZ_H1    ((long long)CHUNK_ROWS*FF_)   // FF hidden, one chunk
#define OFF_KM   (OFF_H1 + SZ_H1)
#define SZ_KM    (64*128)
#define OFF_KVAGG (OFF_KM + SZ_KM)
#define SZ_KVAGG (64*8192)
#define OFF_BMAT (OFF_KVAGG + SZ_KVAGG)
#define SZ_BMAT  (64*8192)
#define OFF_Z1   (OFF_BMAT + SZ_BMAT)
#define SZ_Z     (64LL*N_)
#define OFF_Z2   (OFF_Z1 + SZ_Z)
#define OFF_SC   (OFF_Z2 + SZ_Z)
#define OFF_PW   (OFF_SC + 512)
#define WS_FLOATS (OFF_PW + 512)

__device__ __forceinline__ float safe_pow(float x, float p) {
    return x > 0.f ? powf(x, p) : 0.f;
}

__global__ void zero_kernel(float* __restrict__ p, long long n) {
    long long i = (long long)blockIdx.x*256 + threadIdx.x;
    if (i < n) p[i] = 0.f;
}

__global__ void prep_params(const float* __restrict__ sp, const float* __restrict__ pp,
                            float* __restrict__ sc, float* __restrict__ pw) {
    int c = blockIdx.x * blockDim.x + threadIdx.x;
    if (c < 512) {
        sc[c] = log1pf(expf(sp[c]));                 // softplus
        pw[c] = 1.f + 4.f / (1.f + expf(-pp[c]));    // 1 + ALPHA*sigmoid
    }
}

// ---------------- generic 64x64x16 fp32 GEMM, templated epilogue/A-loader ----------------
// EPI 0: plain store
// EPI 1: relu(acc + e0[col])
// EPI 2: acc + e0[col] + e1[row*ldr+col]   (bias + residual; e1 may alias Cb elementwise)
// EPI 3: Wqg epilogue: col<512 -> qraw=q/scale -> e2; col>=512 -> g to Cm
// EPI 4: Wkv epilogue: col<512 -> (k + pos[n,col]) / scale; col>=512 -> v raw
// ALOAD 1: A element (row,k) = safe_pow(+-qraw[row*lda + (k&63) + head*64], pw), head = z&7, pw in e0
template<int EPI, int ALOAD>
__global__ __launch_bounds__(256) void gemm_k(
    const float* __restrict__ A, int lda,
    const float* __restrict__ Bm, int ldb,
    float* __restrict__ Cm, int ldc,
    int Ktot,
    const float* __restrict__ e0, const float* __restrict__ e1,
    float* __restrict__ e2, int ldr,
    long long oA_hi, long long oA_lo, long long oB_hi, long long oB_lo,
    long long oC_hi, long long oC_lo)
{
    int z = blockIdx.z;
    const float* Ab = A + oA_hi*(long long)(z>>3) + oA_lo*(long long)(z&7);
    const float* Bb = Bm + oB_hi*(long long)(z>>3) + oB_lo*(long long)(z&7);
    float* Cb = Cm + oC_hi*(long long)(z>>3) + oC_lo*(long long)(z&7);
    const float* pwh = (ALOAD == 1) ? (e0 + (z&7)*64) : nullptr;

    const int m0 = blockIdx.y * 64, n0 = blockIdx.x * 64;
    const int tid = threadIdx.x;
    const int ty = tid >> 4, tx = tid & 15;
    const int arow = tid >> 2, acol = (tid & 3) * 4;
    const int brow = tid >> 4, bcol = (tid & 15) * 4;

    __shared__ float As[16][68];
    __shared__ float Bs[16][68];

    float acc[4][4] = {};

    for (int k0 = 0; k0 < Ktot; k0 += 16) {
        float4 av;
        if constexpr (ALOAD == 1) {
            int kk = k0 + acol;
            int kb = kk & 63;
            float4 raw = *(const float4*)(Ab + (long long)(m0 + arow) * lda + kb);
            float sgn = (kk >= 64) ? -1.f : 1.f;
            av.x = safe_pow(sgn*raw.x, pwh[kb+0]);
            av.y = safe_pow(sgn*raw.y, pwh[kb+1]);
            av.z = safe_pow(sgn*raw.z, pwh[kb+2]);
            av.w = safe_pow(sgn*raw.w, pwh[kb+3]);
        } else {
            av = *(const float4*)(Ab + (long long)(m0 + arow) * lda + k0 + acol);
        }
        float4 bv = *(const float4*)(Bb + (long long)(k0 + brow) * ldb + n0 + bcol);
        __syncthreads();
        As[acol+0][arow] = av.x;
        As[acol+1][arow] = av.y;
        As[acol+2][arow] = av.z;
        As[acol+3][arow] = av.w;
        *(float4*)&Bs[brow][bcol] = bv;
        __syncthreads();
#pragma unroll
        for (int kk = 0; kk < 16; ++kk) {
            float4 a4 = *(const float4*)&As[kk][ty*4];
            float4 b4 = *(const float4*)&Bs[kk][tx*4];
            float ar[4] = {a4.x, a4.y, a4.z, a4.w};
            float br[4] = {b4.x, b4.y, b4.z, b4.w};
#pragma unroll
            for (int i = 0; i < 4; ++i)
#pragma unroll
                for (int j = 0; j < 4; ++j)
                    acc[i][j] = fmaf(ar[i], br[j], acc[i][j]);
        }
    }

#pragma unroll
    for (int i = 0; i < 4; ++i) {
        long long row = m0 + ty*4 + i;
#pragma unroll
        for (int j = 0; j < 4; ++j) {
            int col = n0 + tx*4 + j;
            float v = acc[i][j];
            if constexpr (EPI == 0) {
                Cb[row*(long long)ldc + col] = v;
            } else if constexpr (EPI == 1) {
                Cb[row*(long long)ldc + col] = fmaxf(v + e0[col], 0.f);
            } else if constexpr (EPI == 2) {
                Cb[row*(long long)ldc + col] = v + e0[col] + e1[row*(long long)ldr + col];
            } else if constexpr (EPI == 3) {
                if (col < 512) {
                    e2[row*512 + col] = v / e0[col];
                } else {
                    Cb[row*(long long)ldc + (col - 512)] = v;
                }
            } else if constexpr (EPI == 4) {
                if (col < 512) {
                    int n = (int)(row % N_);
                    Cb[row*(long long)ldc + col] = (v + e1[(long long)n*512 + col]) / e0[col];
                } else {
                    Cb[row*(long long)ldc + col] = v;
                }
            }
        }
    }
}

// km[zb][t] = sum_n kc[b,h,n,t]  (kc recomputed from transformed k), atomic-accumulated
__global__ __launch_bounds__(128) void km_kernel(const float* __restrict__ kvbuf,
                                                 const float* __restrict__ pw,
                                                 float* __restrict__ km)
{
    int zb = blockIdx.x;            // b*8+h
    int b = zb >> 3, h = zb & 7;
    int chunk = blockIdx.y;         // 16 chunks x 196 n
    int tid = threadIdx.x;          // 0..127
    int d = tid & 63;
    bool neg = tid >= 64;
    float p = pw[h*64 + d];
    float s = 0.f;
    int nlo = chunk * 196;
    for (int n = nlo; n < nlo + 196; ++n) {
        float k = kvbuf[((long long)(b*N_ + n))*1024 + h*64 + d];
        float xx = neg ? -k : k;
        s += (xx > 0.f) ? powf(xx, p) : 0.f;
    }
    atomicAdd(&km[zb*128 + tid], s);
}

// kvagg[zb][d2][m] = sum_n kc[n,d2] * v[n,m]   (atomic-accumulated)
__global__ __launch_bounds__(256) void kvagg_kernel(const float* __restrict__ kvbuf,
                                                    const float* __restrict__ pw,
                                                    float* __restrict__ kvagg)
{
    int zb = blockIdx.x;
    int b = zb >> 3, h = zb & 7;
    int chunk = blockIdx.y;         // 8 chunks x 392 n
    int tid = threadIdx.x;
    __shared__ float kcl[128];
    __shared__ float vl[64];
    float acc[32] = {};
    int m = tid & 63, dq = tid >> 6;   // dq in [0,4)
    int nlo = chunk * 392;
    for (int n = nlo; n < nlo + 392; ++n) {
        long long rb = ((long long)(b*N_ + n))*1024;
        __syncthreads();
        if (tid < 64) {
            vl[tid] = kvbuf[rb + 512 + h*64 + tid];
        } else if (tid < 192) {
            int id = tid - 64;
            int d = id & 63;
            bool neg = id >= 64;
            float k = kvbuf[rb + h*64 + d];
            float xx = neg ? -k : k;
            kcl[(neg ? 64 : 0) + d] = (xx > 0.f) ? powf(xx, pw[h*64 + d]) : 0.f;
        }
        __syncthreads();
        float vm = vl[m];
#pragma unroll
        for (int j = 0; j < 32; ++j)
            acc[j] = fmaf(kcl[dq + j*4], vm, acc[j]);
    }
    for (int j = 0; j < 32; ++j)
        atomicAdd(&kvagg[(long long)zb*8192 + (dq + j*4)*64 + m], acc[j]);
}

// Bmat[z][d][j] = kvagg[z][ j<32 ? d : (d+64)%128 ][j] / N
__global__ void bmat_kernel(const float* __restrict__ kvagg, float* __restrict__ bmat) {
    int idx = blockIdx.x * 256 + threadIdx.x;     // < 64*8192
    int z = idx >> 13, r = idx & 8191;
    int d = r >> 6, j = r & 63;
    int sd = (j < 32) ? d : ((d + 64) & 127);
    bmat[idx] = kvagg[((long long)z << 13) + (sd << 6) + j] * (1.0f / (float)N_);
}

// z1/z2 per (b,h,n): 1/(q_sim.km_mean + 1e-6), 1/(q_opp.km_mean + 1e-6); powers on the fly
__global__ __launch_bounds__(256) void z_kernel(const float* __restrict__ qraw,
                                                const float* __restrict__ pw,
                                                const float* __restrict__ km,
                                                float* __restrict__ z1, float* __restrict__ z2)
{
    int zb = blockIdx.x;
    int b = zb >> 3, h = zb & 7;
    int n0 = blockIdx.y * 64;
    __shared__ float kmn[128];
    __shared__ float q[64][129];
    int tid = threadIdx.x;
    if (tid < 128) kmn[tid] = km[zb*128 + tid] * (1.0f / (float)N_);
    for (int i = tid; i < 64*64; i += 256) {
        int nl = i >> 6, d = i & 63;
        float qv = qraw[((long long)(b*N_ + n0 + nl))*512 + h*64 + d];
        float p = pw[h*64 + d];
        q[nl][d]      = safe_pow(qv, p);
        q[nl][d + 64] = safe_pow(-qv, p);
    }
    __syncthreads();
    int nl = tid >> 2, qtr = tid & 3;
    float p1 = 0.f, p2 = 0.f;
    int d0 = qtr * 32;
    for (int d = d0; d < d0 + 32; ++d) {
        p1 = fmaf(q[nl][d], kmn[d], p1);
        p2 = fmaf(q[nl][(d + 64) & 127], kmn[d], p2);
    }
    p1 += __shfl_xor(p1, 1); p1 += __shfl_xor(p1, 2);
    p2 += __shfl_xor(p2, 1); p2 += __shfl_xor(p2, 2);
    if (qtr == 0) {
        int n = n0 + nl;
        z1[(long long)zb*N_ + n] = 1.0f / (p1 + 1e-6f);
        z2[(long long)zb*N_ + n] = 1.0f / (p2 + 1e-6f);
    }
}

// depthwise 5x5 conv on v + z-scale attn + gate:  x2 = (attn*z + conv(v)+b)*g  -> out
__global__ __launch_bounds__(256) void conv_combine(
    const float* __restrict__ kvbuf, const float* __restrict__ dwc_w,
    const float* __restrict__ dwc_b, const float* __restrict__ z1,
    const float* __restrict__ z2, const float* __restrict__ gbuf,
    float* __restrict__ out)
{
    __shared__ float w[1600];
    __shared__ float bb[64];
    int tid = threadIdx.x;
    for (int i = tid; i < 1600; i += 256) w[i] = dwc_w[i];
    if (tid < 64) bb[tid] = dwc_b[tid];
    __syncthreads();
    int blk = blockIdx.x;
    int chalf = blk & 1;
    int by = blk >> 1;
    int b = by / 56, y = by % 56;
    for (int idx = tid; idx < 56*256; idx += 256) {
        int xx0 = idx >> 8;
        int c = chalf*256 + (idx & 255);
        int h = c >> 6, hd = c & 63;
        float sum = bb[hd];
#pragma unroll
        for (int ky = 0; ky < 5; ++ky) {
            int yy = y + ky - 2;
            if ((unsigned)yy < 56u) {
                long long rowbase = ((long long)(b*N_ + yy*56))*1024 + 512 + c;
#pragma unroll
                for (int kx = 0; kx < 5; ++kx) {
                    int xv = xx0 + kx - 2;
                    if ((unsigned)xv < 56u)
                        sum = fmaf(w[hd*25 + ky*5 + kx], kvbuf[rowbase + (long long)xv*1024], sum);
                }
            }
        }
        int n = y*56 + xx0;
        long long row = (long long)b*N_ + n;
        float zz = (hd < 32 ? z1 : z2)[(long long)(b*8 + h)*N_ + n];
        float attn = kvbuf[row*1024 + c] * zz;
        float g = gbuf[row*512 + c];
        out[row*512 + c] = (attn + sum) * g;
    }
}

// layernorm over C=512, in place on d_out; 4 rows per block (one per wave)
__global__ __launch_bounds__(256) void ln_kernel(float* __restrict__ y,
                                                 const float* __restrict__ g,
                                                 const float* __restrict__ bta)
{
    int wid = threadIdx.x >> 6, lane = threadIdx.x & 63;
    long long row = (long long)blockIdx.x*4 + wid;
    float v[8];
    float s = 0.f, s2 = 0.f;
#pragma unroll
    for (int i = 0; i < 8; ++i) {
        v[i] = y[row*512 + i*64 + lane];
        s += v[i];
        s2 = fmaf(v[i], v[i], s2);
    }
#pragma unroll
    for (int o = 32; o > 0; o >>= 1) { s += __shfl_xor(s, o); s2 += __shfl_xor(s2, o); }
    float mu = s * (1.f/512.f);
    float var = s2 * (1.f/512.f) - mu*mu;
    float rstd = rsqrtf(var + 1e-5f);
#pragma unroll
    for (int i = 0; i < 8; ++i) {
        int c = i*64 + lane;
        y[row*512 + c] = (v[i] - mu) * rstd * g[c] + bta[c];
    }
}

extern "C" void kernel_launch(void* const* d_in, const int* in_sizes, int n_in,
                              void* d_out, int out_size, void* d_ws, size_t ws_size,
                              hipStream_t stream)
{
    (void)in_sizes; (void)n_in; (void)out_size;
    if (ws_size < (size_t)WS_FLOATS * sizeof(float)) return;  // diagnostic: fail loud, not crash

    const float* x       = (const float*)d_in[0];
    const float* Wqg     = (const float*)d_in[1];
    const float* Wkv     = (const float*)d_in[2];
    const float* pos     = (const float*)d_in[3];
    const float* scale_p = (const float*)d_in[4];
    const float* power_p = (const float*)d_in[5];
    const float* dwc_w   = (const float*)d_in[6];
    const float* dwc_b   = (const float*)d_in[7];
    const float* ln_g    = (const float*)d_in[8];
    const float* ln_b    = (const float*)d_in[9];
    const float* W1      = (const float*)d_in[10];
    const float* b1      = (const float*)d_in[11];
    const float* W2      = (const float*)d_in[12];
    const float* b2      = (const float*)d_in[13];
    float* out = (float*)d_out;
    float* ws  = (float*)d_ws;

    float* kvbuf = ws + OFF_KV;
    float* qraw  = ws + OFF_Q;
    float* gbuf  = ws + OFF_G;
    float* h1    = ws + OFF_H1;
    float* km    = ws + OFF_KM;
    float* kvagg = ws + OFF_KVAGG;
    float* bmat  = ws + OFF_BMAT;
    float* z1    = ws + OFF_Z1;
    float* z2    = ws + OFF_Z2;
    float* sc    = ws + OFF_SC;
    float* pw    = ws + OFF_PW;

    prep_params<<<2, 256, 0, stream>>>(scale_p, power_p, sc, pw);
    zero_kernel<<<(SZ_KM + SZ_KVAGG + 255)/256, 256, 0, stream>>>(km, SZ_KM + SZ_KVAGG);

    // qg = x@Wqg: epilogue -> qraw (q/scale) + g
    gemm_k<3,0><<<dim3(16, 392, 1), 256, 0, stream>>>(x, 512, Wqg, 1024, gbuf, 512, 512,
                                                      sc, nullptr, qraw, 0, 0,0,0,0,0,0);
    // kv = x@Wkv: epilogue -> k=(k+pos)/scale, v raw
    gemm_k<4,0><<<dim3(16, 392, 1), 256, 0, stream>>>(x, 512, Wkv, 1024, kvbuf, 1024, 512,
                                                      sc, pos, nullptr, 0, 0,0,0,0,0,0);

    km_kernel<<<dim3(64, 16), 128, 0, stream>>>(kvbuf, pw, km);
    kvagg_kernel<<<dim3(64, 8), 256, 0, stream>>>(kvbuf, pw, kvagg);
    bmat_kernel<<<2048, 256, 0, stream>>>(kvagg, bmat);
    z_kernel<<<dim3(64, 49), 256, 0, stream>>>(qraw, pw, km, z1, z2);

    // attn_raw = qs @ Bmat (batched over 64 (b,h)); qs computed on the fly from qraw.
    // Writes into dead k-half of kvbuf.
    gemm_k<0,1><<<dim3(1, 49, 64), 256, 0, stream>>>(qraw, 512, bmat, 64, kvbuf, 1024, 128,
                                                     pw, nullptr, nullptr, 0,
                                                     (long long)N_*512, 64,
                                                     8LL*8192, 8192,
                                                     (long long)N_*1024, 64);

    conv_combine<<<dim3(896), 256, 0, stream>>>(kvbuf, dwc_w, dwc_b, z1, z2, gbuf, out);

    for (int chunk = 0; chunk < N_CHUNKS; ++chunk) {
        float* x2c = out + (long long)chunk*CHUNK_ROWS*512;
        gemm_k<1,0><<<dim3(64, CHUNK_ROWS/64, 1), 256, 0, stream>>>(
            x2c, 512, W1, 4096, h1, 4096, 512,
            b1, nullptr, nullptr, 0, 0,0,0,0,0,0);
        gemm_k<2,0><<<dim3(8, CHUNK_ROWS/64, 1), 256, 0, stream>>>(
            h1, 4096, W2, 512, x2c, 512, 4096,
            b2, x2c, nullptr, 512, 0,0,0,0,0,0);
    }

    ln_kernel<<<6272, 256, 0, stream>>>(out, ln_g, ln_b);
}

// Round 3
// 1533.128 us; speedup vs baseline: 4.1614x; 4.1614x over previous
//
#include <hip/hip_runtime.h>
#include <hip/hip_bf16.h>

#define B_ 8
#define N_ 3136
#define C_ 512
#define NH_ 8
#define HD_ 64
#define FF_ 4096
#define M_ (B_*N_)   // 25088
#define FFCHUNK 12544   // rows per FF chunk (2 chunks)

// ---- workspace layout (byte offsets), total ~211.6 MB ----
#define SZF 51380224LL            // f32 M*512
#define SZH 25690112LL            // bf16 M*512
#define OFF_KRAW 0LL              // f32 (k+pos)/scale        [dead after kvagg]
#define OFF_QRAW (OFF_KRAW + SZF) // f32 q/scale              [dead after attn]
#define OFF_XB   (OFF_QRAW + SZF) // bf16 x                   [dead after Wkv gemm]
#define OFF_VB   (OFF_XB + SZH)   // bf16 v
#define OFF_ATTN (OFF_VB + SZH)   // bf16 z-scaled attn
#define OFF_GX2  (OFF_ATTN + SZH) // bf16 g, overwritten in-place by x2
#define OFF_WQGT (OFF_GX2 + SZH)  // bf16 1024x512
#define OFF_WKVT (OFF_WQGT + 1048576LL)
#define OFF_W1T  (OFF_WKVT + 1048576LL)  // bf16 4096x512
#define OFF_W2T  (OFF_W1T + 4194304LL)   // bf16 512x4096
#define OFF_KM   (OFF_W2T + 4194304LL)   // f32 64*128
#define OFF_KVAGG (OFF_KM + 32768LL)     // f32 64*8192
#define OFF_BMAT (OFF_KVAGG + 2097152LL) // f32 64*8192
#define OFF_Z1   (OFF_BMAT + 2097152LL)  // f32 64*3136
#define OFF_Z2   (OFF_Z1 + 802816LL)
#define OFF_SC   (OFF_Z2 + 802816LL)
#define OFF_PW   (OFF_SC + 2048LL)
#define WS_BYTES (OFF_PW + 2048LL)
// h1b (bf16 12544*4096 = 102,760,448 B) aliases [OFF_KRAW, OFF_XB) exactly.
#define OFF_H1B  0LL

typedef short bfrag __attribute__((ext_vector_type(8)));
typedef float ffrag __attribute__((ext_vector_type(4)));

__device__ __forceinline__ float safe_pow(float x, float p) {
    return x > 0.f ? powf(x, p) : 0.f;
}

__device__ __forceinline__ void gld_lds16(const void* g, void* l) {
    __builtin_amdgcn_global_load_lds(
        (const __attribute__((address_space(1))) unsigned int*)g,
        (__attribute__((address_space(3))) unsigned int*)l, 16, 0, 0);
}

__global__ void zero_kernel(float* __restrict__ p, long long n) {
    long long i = (long long)blockIdx.x*256 + threadIdx.x;
    if (i < n) p[i] = 0.f;
}

__global__ void prep_params(const float* __restrict__ sp, const float* __restrict__ pp,
                            float* __restrict__ sc, float* __restrict__ pw) {
    int c = blockIdx.x * blockDim.x + threadIdx.x;
    if (c < 512) {
        sc[c] = log1pf(expf(sp[c]));
        pw[c] = 1.f + 4.f / (1.f + expf(-pp[c]));
    }
}

__global__ void cvt_bf16_kernel(const float* __restrict__ s, __hip_bfloat16* __restrict__ d,
                                long long n) {
    long long i = ((long long)blockIdx.x*256 + threadIdx.x)*4;
    if (i < n) {
        float4 v = *(const float4*)(s + i);
        union { __hip_bfloat16 h[4]; uint2 u; } t;
        t.h[0] = __float2bfloat16(v.x);
        t.h[1] = __float2bfloat16(v.y);
        t.h[2] = __float2bfloat16(v.z);
        t.h[3] = __float2bfloat16(v.w);
        *(uint2*)(d + i) = t.u;
    }
}

// src R x C fp32 -> dst C x R bf16
__global__ __launch_bounds__(256) void transpose_cvt(const float* __restrict__ s,
        __hip_bfloat16* __restrict__ d, int R, int Cc) {
    __shared__ float t[32][33];
    int c0 = blockIdx.x*32, r0 = blockIdx.y*32;
    int tx = threadIdx.x & 31, ty = threadIdx.x >> 5;
#pragma unroll
    for (int i = 0; i < 32; i += 8)
        t[ty+i][tx] = s[(long long)(r0+ty+i)*Cc + c0+tx];
    __syncthreads();
#pragma unroll
    for (int i = 0; i < 32; i += 8)
        d[(long long)(c0+ty+i)*R + r0+tx] = __float2bfloat16(t[tx][ty+i]);
}

// ---------------- 128x128 bf16 MFMA GEMM ----------------
// C = A(MxK) @ Bt^T where Bt is N x K (pre-transposed), both bf16, fp32 accum.
// EPI 0 (QG): col<512 -> o0[row*512+col] = acc/p0[col]; else o1 bf16(acc) (g)
// EPI 1 (KV): col<512 -> o0 = (acc + p1[n*512+col])/p0[col]; else o1 bf16(acc) (v)
// EPI 2 (FF1): o1[row*ldo+col] = bf16(relu(acc + p0[col]))
// EPI 3 (FF2): o0[row*512+col] += acc + p0[col]   (residual already in o0)
template<int EPI>
__global__ __launch_bounds__(256) void gemm_mfma(
    const __hip_bfloat16* __restrict__ A, int lda,
    const __hip_bfloat16* __restrict__ Bt, int ldbt,
    int Ktot, int ldo,
    float* __restrict__ o0, __hip_bfloat16* __restrict__ o1,
    const float* __restrict__ p0, const float* __restrict__ p1)
{
    __shared__ __hip_bfloat16 As[128*32];
    __shared__ __hip_bfloat16 Bs[128*32];
    const int tid = threadIdx.x;
    const int lane = tid & 63, w = tid >> 6;
    const int wm = w >> 1, wn = w & 1;
    const int quad = lane >> 4, l16 = lane & 15;
    const int m0 = blockIdx.y * 128, n0 = blockIdx.x * 128;
    const int srow = lane >> 2;          // 0..15
    const int scol = (lane & 3) * 8;     // bf16 elements

    ffrag acc[4][4];
#pragma unroll
    for (int i = 0; i < 4; ++i)
#pragma unroll
        for (int j = 0; j < 4; ++j)
#pragma unroll
            for (int r = 0; r < 4; ++r) acc[i][j][r] = 0.f;

    for (int k0 = 0; k0 < Ktot; k0 += 32) {
        __syncthreads();
#pragma unroll
        for (int t = 0; t < 2; ++t) {
            const __hip_bfloat16* gp = A + (long long)(m0 + t*64 + w*16 + srow)*lda + k0 + scol;
            gld_lds16(gp, As + (t*64 + w*16)*32);
        }
#pragma unroll
        for (int t = 0; t < 2; ++t) {
            const __hip_bfloat16* gp = Bt + (long long)(n0 + t*64 + w*16 + srow)*ldbt + k0 + scol;
            gld_lds16(gp, Bs + (t*64 + w*16)*32);
        }
        __syncthreads();
        bfrag af[4], bf[4];
#pragma unroll
        for (int i = 0; i < 4; ++i)
            af[i] = *(const bfrag*)(As + (wm*64 + i*16 + l16)*32 + quad*8);
#pragma unroll
        for (int j = 0; j < 4; ++j)
            bf[j] = *(const bfrag*)(Bs + (wn*64 + j*16 + l16)*32 + quad*8);
#pragma unroll
        for (int i = 0; i < 4; ++i)
#pragma unroll
            for (int j = 0; j < 4; ++j)
                acc[i][j] = __builtin_amdgcn_mfma_f32_16x16x32_bf16(af[i], bf[j], acc[i][j], 0, 0, 0);
    }

#pragma unroll
    for (int i = 0; i < 4; ++i) {
        int rbase = m0 + wm*64 + i*16 + quad*4;
#pragma unroll
        for (int r = 0; r < 4; ++r) {
            long long grow = rbase + r;
            int nmod = 0;
            if constexpr (EPI == 1) nmod = (int)(grow % N_);
#pragma unroll
            for (int j = 0; j < 4; ++j) {
                int gcol = n0 + wn*64 + j*16 + l16;
                float v = acc[i][j][r];
                if constexpr (EPI == 0) {
                    if (gcol < 512) o0[grow*512 + gcol] = v / p0[gcol];
                    else o1[grow*512 + gcol - 512] = __float2bfloat16(v);
                } else if constexpr (EPI == 1) {
                    if (gcol < 512) o0[grow*512 + gcol] = (v + p1[(long long)nmod*512 + gcol]) / p0[gcol];
                    else o1[grow*512 + gcol - 512] = __float2bfloat16(v);
                } else if constexpr (EPI == 2) {
                    o1[grow*(long long)ldo + gcol] = __float2bfloat16(fmaxf(v + p0[gcol], 0.f));
                } else {
                    o0[grow*512 + gcol] = o0[grow*512 + gcol] + v + p0[gcol];
                }
            }
        }
    }
}

// kvagg[zb][d2][m] = sum_n kc[n,d2]*v[n,m]; km[zb][d2] = sum_n kc[n,d2]. 16 n per barrier round.
__global__ __launch_bounds__(256) void kvagg_kernel(const float* __restrict__ kraw,
                                                    const __hip_bfloat16* __restrict__ vb,
                                                    const float* __restrict__ pw,
                                                    float* __restrict__ km,
                                                    float* __restrict__ kvagg)
{
    int zb = blockIdx.x;            // b*8+h
    int b = zb >> 3, h = zb & 7;
    int chunk = blockIdx.y;         // 16 chunks x 196 n
    int tid = threadIdx.x;
    __shared__ float kcl[16][128];
    __shared__ float vl[16][64];
    float acc[32];
#pragma unroll
    for (int j = 0; j < 32; ++j) acc[j] = 0.f;
    float kmacc = 0.f;
    const int dd = tid & 63;
    const float p = pw[h*64 + dd];
    const int m = tid & 63, dq = tid >> 6;
    for (int r = 0; r < 13; ++r) {
        int n0 = chunk*196 + r*16;
        int cnt = (r < 12) ? 16 : 4;
        __syncthreads();
#pragma unroll
        for (int i = 0; i < 4; ++i) {
            int nl = (tid >> 6) + i*4;
            if (nl < cnt) {
                long long rb = ((long long)(b*N_ + n0 + nl))*512 + h*64 + dd;
                float kv_ = kraw[rb];
                kcl[nl][dd]      = kv_ > 0.f ? powf(kv_, p) : 0.f;
                kcl[nl][64 + dd] = kv_ < 0.f ? powf(-kv_, p) : 0.f;
                vl[nl][dd] = __bfloat162float(vb[rb]);
            }
        }
        __syncthreads();
        for (int nl = 0; nl < cnt; ++nl) {
            float vm = vl[nl][m];
            const float4* kp = (const float4*)&kcl[nl][dq*32];
#pragma unroll
            for (int j4 = 0; j4 < 8; ++j4) {
                float4 kk = kp[j4];
                acc[j4*4+0] = fmaf(kk.x, vm, acc[j4*4+0]);
                acc[j4*4+1] = fmaf(kk.y, vm, acc[j4*4+1]);
                acc[j4*4+2] = fmaf(kk.z, vm, acc[j4*4+2]);
                acc[j4*4+3] = fmaf(kk.w, vm, acc[j4*4+3]);
            }
        }
        if (tid < 128) {
            for (int nl = 0; nl < cnt; ++nl) kmacc += kcl[nl][tid];
        }
    }
#pragma unroll
    for (int j = 0; j < 32; ++j)
        atomicAdd(&kvagg[(long long)zb*8192 + (dq*32 + j)*64 + m], acc[j]);
    if (tid < 128) atomicAdd(&km[zb*128 + tid], kmacc);
}

// Bmat[z][d][j] = kvagg[z][ j<32 ? d : (d+64)%128 ][j] / N
__global__ void bmat_kernel(const float* __restrict__ kvagg, float* __restrict__ bmat) {
    int idx = blockIdx.x * 256 + threadIdx.x;     // < 64*8192
    int z = idx >> 13, r = idx & 8191;
    int d = r >> 6, j = r & 63;
    int sd = (j < 32) ? d : ((d + 64) & 127);
    bmat[idx] = kvagg[((long long)z << 13) + (sd << 6) + j] * (1.0f / (float)N_);
}

// z1/z2 per (b,h,n)
__global__ __launch_bounds__(256) void z_kernel(const float* __restrict__ qraw,
                                                const float* __restrict__ pw,
                                                const float* __restrict__ km,
                                                float* __restrict__ z1, float* __restrict__ z2)
{
    int zb = blockIdx.x;
    int b = zb >> 3, h = zb & 7;
    int n0 = blockIdx.y * 64;
    __shared__ float kmn[128];
    __shared__ float q[64][129];
    int tid = threadIdx.x;
    if (tid < 128) kmn[tid] = km[zb*128 + tid] * (1.0f / (float)N_);
    for (int i = tid; i < 64*64; i += 256) {
        int nl = i >> 6, d = i & 63;
        float qv = qraw[((long long)(b*N_ + n0 + nl))*512 + h*64 + d];
        float p = pw[h*64 + d];
        q[nl][d]      = safe_pow(qv, p);
        q[nl][d + 64] = safe_pow(-qv, p);
    }
    __syncthreads();
    int nl = tid >> 2, qtr = tid & 3;
    float p1 = 0.f, p2 = 0.f;
    int d0 = qtr * 32;
    for (int d = d0; d < d0 + 32; ++d) {
        p1 = fmaf(q[nl][d], kmn[d], p1);
        p2 = fmaf(q[nl][(d + 64) & 127], kmn[d], p2);
    }
    p1 += __shfl_xor(p1, 1); p1 += __shfl_xor(p1, 2);
    p2 += __shfl_xor(p2, 1); p2 += __shfl_xor(p2, 2);
    if (qtr == 0) {
        int n = n0 + nl;
        z1[(long long)zb*N_ + n] = 1.0f / (p1 + 1e-6f);
        z2[(long long)zb*N_ + n] = 1.0f / (p2 + 1e-6f);
    }
}

// attn = (qs @ bmat) * z -> bf16; qs powers computed on the fly from qraw
__global__ __launch_bounds__(256) void attn_gemm(const float* __restrict__ qraw,
                                                 const float* __restrict__ bmat,
                                                 const float* __restrict__ pw,
                                                 const float* __restrict__ z1,
                                                 const float* __restrict__ z2,
                                                 __hip_bfloat16* __restrict__ attnb)
{
    int zb = blockIdx.y;
    int b = zb >> 3, h = zb & 7;
    const float* Ab = qraw + (long long)b*N_*512 + h*64;
    const float* Bb = bmat + (long long)zb*8192;
    const float* pwh = pw + h*64;
    const int m0 = blockIdx.x * 64;
    const int tid = threadIdx.x;
    const int ty = tid >> 4, tx = tid & 15;
    const int arow = tid >> 2, acol = (tid & 3) * 4;
    const int brow = tid >> 4, bcol = (tid & 15) * 4;

    __shared__ float As[16][68];
    __shared__ float Bs[16][68];
    float acc[4][4] = {};

    for (int k0 = 0; k0 < 128; k0 += 16) {
        int kk = k0 + acol;
        int kb = kk & 63;
        float4 raw = *(const float4*)(Ab + (long long)(m0 + arow)*512 + kb);
        float sgn = (kk >= 64) ? -1.f : 1.f;
        float4 av;
        av.x = safe_pow(sgn*raw.x, pwh[kb+0]);
        av.y = safe_pow(sgn*raw.y, pwh[kb+1]);
        av.z = safe_pow(sgn*raw.z, pwh[kb+2]);
        av.w = safe_pow(sgn*raw.w, pwh[kb+3]);
        float4 bv = *(const float4*)(Bb + (long long)(k0 + brow)*64 + bcol);
        __syncthreads();
        As[acol+0][arow] = av.x;
        As[acol+1][arow] = av.y;
        As[acol+2][arow] = av.z;
        As[acol+3][arow] = av.w;
        *(float4*)&Bs[brow][bcol] = bv;
        __syncthreads();
#pragma unroll
        for (int kx = 0; kx < 16; ++kx) {
            float4 a4 = *(const float4*)&As[kx][ty*4];
            float4 b4 = *(const float4*)&Bs[kx][tx*4];
            float ar[4] = {a4.x, a4.y, a4.z, a4.w};
            float br[4] = {b4.x, b4.y, b4.z, b4.w};
#pragma unroll
            for (int i = 0; i < 4; ++i)
#pragma unroll
                for (int j = 0; j < 4; ++j)
                    acc[i][j] = fmaf(ar[i], br[j], acc[i][j]);
        }
    }
#pragma unroll
    for (int i = 0; i < 4; ++i) {
        int row = m0 + ty*4 + i;
#pragma unroll
        for (int j = 0; j < 4; ++j) {
            int col = tx*4 + j;
            float zz = ((col < 32) ? z1 : z2)[(long long)zb*N_ + row];
            attnb[((long long)(b*N_ + row))*512 + h*64 + col] = __float2bfloat16(acc[i][j] * zz);
        }
    }
}

// x2 = (attn + conv(v)+b)*g -> out (f32) and gx2 (bf16, in-place over g)
__global__ __launch_bounds__(256) void conv_combine(
    const __hip_bfloat16* __restrict__ vb, const float* __restrict__ dwc_w,
    const float* __restrict__ dwc_b, const __hip_bfloat16* __restrict__ attnb,
    __hip_bfloat16* __restrict__ gx2, float* __restrict__ out)
{
    __shared__ float w[1600];
    __shared__ float bb[64];
    int tid = threadIdx.x;
    for (int i = tid; i < 1600; i += 256) w[i] = dwc_w[i];
    if (tid < 64) bb[tid] = dwc_b[tid];
    __syncthreads();
    int blk = blockIdx.x;
    int chalf = blk & 1;
    int by = blk >> 1;
    int b = by / 56, y = by % 56;
    for (int idx = tid; idx < 56*256; idx += 256) {
        int xx0 = idx >> 8;
        int c = chalf*256 + (idx & 255);
        int hd = c & 63;
        float sum = bb[hd];
#pragma unroll
        for (int ky = 0; ky < 5; ++ky) {
            int yy = y + ky - 2;
            if ((unsigned)yy < 56u) {
                long long rowbase = ((long long)(b*N_ + yy*56))*512 + c;
#pragma unroll
                for (int kx = 0; kx < 5; ++kx) {
                    int xv = xx0 + kx - 2;
                    if ((unsigned)xv < 56u)
                        sum = fmaf(w[hd*25 + ky*5 + kx],
                                   __bfloat162float(vb[rowbase + (long long)xv*512]), sum);
                }
            }
        }
        int n = y*56 + xx0;
        long long row = (long long)b*N_ + n;
        float attn = __bfloat162float(attnb[row*512 + c]);
        float g = __bfloat162float(gx2[row*512 + c]);
        float x2 = (attn + sum) * g;
        out[row*512 + c] = x2;
        gx2[row*512 + c] = __float2bfloat16(x2);
    }
}

__global__ __launch_bounds__(256) void ln_kernel(float* __restrict__ y,
                                                 const float* __restrict__ g,
                                                 const float* __restrict__ bta)
{
    int wid = threadIdx.x >> 6, lane = threadIdx.x & 63;
    long long row = (long long)blockIdx.x*4 + wid;
    float v[8];
    float s = 0.f, s2 = 0.f;
#pragma unroll
    for (int i = 0; i < 8; ++i) {
        v[i] = y[row*512 + i*64 + lane];
        s += v[i];
        s2 = fmaf(v[i], v[i], s2);
    }
#pragma unroll
    for (int o = 32; o > 0; o >>= 1) { s += __shfl_xor(s, o); s2 += __shfl_xor(s2, o); }
    float mu = s * (1.f/512.f);
    float var = s2 * (1.f/512.f) - mu*mu;
    float rstd = rsqrtf(var + 1e-5f);
#pragma unroll
    for (int i = 0; i < 8; ++i) {
        int c = i*64 + lane;
        y[row*512 + c] = (v[i] - mu) * rstd * g[c] + bta[c];
    }
}

extern "C" void kernel_launch(void* const* d_in, const int* in_sizes, int n_in,
                              void* d_out, int out_size, void* d_ws, size_t ws_size,
                              hipStream_t stream)
{
    (void)in_sizes; (void)n_in; (void)out_size;
    if (ws_size < (size_t)WS_BYTES) return;  // fail loud (zero output), not crash

    const float* x       = (const float*)d_in[0];
    const float* Wqg     = (const float*)d_in[1];
    const float* Wkv     = (const float*)d_in[2];
    const float* pos     = (const float*)d_in[3];
    const float* scale_p = (const float*)d_in[4];
    const float* power_p = (const float*)d_in[5];
    const float* dwc_w   = (const float*)d_in[6];
    const float* dwc_b   = (const float*)d_in[7];
    const float* ln_g    = (const float*)d_in[8];
    const float* ln_b    = (const float*)d_in[9];
    const float* W1      = (const float*)d_in[10];
    const float* b1      = (const float*)d_in[11];
    const float* W2      = (const float*)d_in[12];
    const float* b2      = (const float*)d_in[13];
    float* out = (float*)d_out;
    char* ws   = (char*)d_ws;

    float* kraw  = (float*)(ws + OFF_KRAW);
    float* qraw  = (float*)(ws + OFF_QRAW);
    __hip_bfloat16* xb   = (__hip_bfloat16*)(ws + OFF_XB);
    __hip_bfloat16* vb   = (__hip_bfloat16*)(ws + OFF_VB);
    __hip_bfloat16* attnb= (__hip_bfloat16*)(ws + OFF_ATTN);
    __hip_bfloat16* gx2  = (__hip_bfloat16*)(ws + OFF_GX2);
    __hip_bfloat16* Wqgt = (__hip_bfloat16*)(ws + OFF_WQGT);
    __hip_bfloat16* Wkvt = (__hip_bfloat16*)(ws + OFF_WKVT);
    __hip_bfloat16* W1t  = (__hip_bfloat16*)(ws + OFF_W1T);
    __hip_bfloat16* W2t  = (__hip_bfloat16*)(ws + OFF_W2T);
    __hip_bfloat16* h1b  = (__hip_bfloat16*)(ws + OFF_H1B);
    float* km    = (float*)(ws + OFF_KM);
    float* kvagg = (float*)(ws + OFF_KVAGG);
    float* bmat  = (float*)(ws + OFF_BMAT);
    float* z1    = (float*)(ws + OFF_Z1);
    float* z2    = (float*)(ws + OFF_Z2);
    float* sc    = (float*)(ws + OFF_SC);
    float* pw    = (float*)(ws + OFF_PW);

    prep_params<<<2, 256, 0, stream>>>(scale_p, power_p, sc, pw);
    zero_kernel<<<(64*128 + 64*8192 + 255)/256, 256, 0, stream>>>(km, 64*128 + 64*8192);
    cvt_bf16_kernel<<<(int)(((long long)M_*512/4 + 255)/256), 256, 0, stream>>>(x, xb, (long long)M_*512);
    transpose_cvt<<<dim3(32, 16), 256, 0, stream>>>(Wqg, Wqgt, 512, 1024);
    transpose_cvt<<<dim3(32, 16), 256, 0, stream>>>(Wkv, Wkvt, 512, 1024);
    transpose_cvt<<<dim3(128, 16), 256, 0, stream>>>(W1, W1t, 512, 4096);
    transpose_cvt<<<dim3(16, 128), 256, 0, stream>>>(W2, W2t, 4096, 512);

    // qg = x@Wqg -> qraw f32 + g bf16
    gemm_mfma<0><<<dim3(8, 196), 256, 0, stream>>>(xb, 512, Wqgt, 512, 512, 0,
                                                   qraw, gx2, sc, nullptr);
    // kv = x@Wkv -> kraw f32 + v bf16
    gemm_mfma<1><<<dim3(8, 196), 256, 0, stream>>>(xb, 512, Wkvt, 512, 512, 0,
                                                   kraw, vb, sc, pos);

    kvagg_kernel<<<dim3(64, 16), 256, 0, stream>>>(kraw, vb, pw, km, kvagg);
    bmat_kernel<<<2048, 256, 0, stream>>>(kvagg, bmat);
    z_kernel<<<dim3(64, 49), 256, 0, stream>>>(qraw, pw, km, z1, z2);
    attn_gemm<<<dim3(49, 64), 256, 0, stream>>>(qraw, bmat, pw, z1, z2, attnb);

    conv_combine<<<dim3(896), 256, 0, stream>>>(vb, dwc_w, dwc_b, attnb, gx2, out);

    for (int c = 0; c < 2; ++c) {
        const __hip_bfloat16* x2c = gx2 + (long long)c*FFCHUNK*512;
        float* outc = out + (long long)c*FFCHUNK*512;
        gemm_mfma<2><<<dim3(32, FFCHUNK/128), 256, 0, stream>>>(
            x2c, 512, W1t, 512, 512, 4096, nullptr, h1b, b1, nullptr);
        gemm_mfma<3><<<dim3(4, FFCHUNK/128), 256, 0, stream>>>(
            h1b, 4096, W2t, 4096, 4096, 0, outc, nullptr, b2, nullptr);
    }

    ln_kernel<<<6272, 256, 0, stream>>>(out, ln_g, ln_b);
}

// Round 4
// 1217.981 us; speedup vs baseline: 5.2381x; 1.2587x over previous
//
#include <hip/hip_runtime.h>
#include <hip/hip_bf16.h>

#define B_ 8
#define N_ 3136
#define C_ 512
#define NH_ 8
#define HD_ 64
#define FF_ 4096
#define M_ (B_*N_)   // 25088
#define FFCHUNK 12544   // rows per FF chunk (2 chunks)

// ---- workspace layout (byte offsets), total ~211.6 MB ----
#define SZF 51380224LL            // f32 M*512
#define SZH 25690112LL            // bf16 M*512
#define OFF_KRAW 0LL              // f32 (k+pos)/scale        [dead after kvagg]
#define OFF_QRAW (OFF_KRAW + SZF) // f32 q/scale              [dead after attn]
#define OFF_XB   (OFF_QRAW + SZF) // bf16 x                   [dead after Wkv gemm]
#define OFF_VB   (OFF_XB + SZH)   // bf16 v
#define OFF_ATTN (OFF_VB + SZH)   // bf16 z-scaled attn
#define OFF_GX2  (OFF_ATTN + SZH) // bf16 g, overwritten in-place by x2
#define OFF_WQGT (OFF_GX2 + SZH)  // bf16 1024x512
#define OFF_WKVT (OFF_WQGT + 1048576LL)
#define OFF_W1T  (OFF_WKVT + 1048576LL)  // bf16 4096x512
#define OFF_W2T  (OFF_W1T + 4194304LL)   // bf16 512x4096
#define OFF_KM   (OFF_W2T + 4194304LL)   // f32 64*128
#define OFF_KVAGG (OFF_KM + 32768LL)     // f32 64*8192
#define OFF_BMAT (OFF_KVAGG + 2097152LL) // f32 64*8192
#define OFF_Z1   (OFF_BMAT + 2097152LL)  // f32 64*3136
#define OFF_Z2   (OFF_Z1 + 802816LL)
#define OFF_SC   (OFF_Z2 + 802816LL)
#define OFF_PW   (OFF_SC + 2048LL)
#define WS_BYTES (OFF_PW + 2048LL)
// h1b (bf16 12544*4096 = 102,760,448 B) aliases [OFF_KRAW, OFF_XB) exactly.
#define OFF_H1B  0LL

typedef short bfrag __attribute__((ext_vector_type(8)));
typedef float ffrag __attribute__((ext_vector_type(4)));

__device__ __forceinline__ float safe_pow(float x, float p) {
    return x > 0.f ? powf(x, p) : 0.f;
}

__device__ __forceinline__ void gld_lds16(const void* g, void* l) {
    __builtin_amdgcn_global_load_lds(
        (const __attribute__((address_space(1))) unsigned int*)g,
        (__attribute__((address_space(3))) unsigned int*)l, 16, 0, 0);
}

__global__ void zero_kernel(float* __restrict__ p, long long n) {
    long long i = (long long)blockIdx.x*256 + threadIdx.x;
    if (i < n) p[i] = 0.f;
}

__global__ void prep_params(const float* __restrict__ sp, const float* __restrict__ pp,
                            float* __restrict__ sc, float* __restrict__ pw) {
    int c = blockIdx.x * blockDim.x + threadIdx.x;
    if (c < 512) {
        sc[c] = log1pf(expf(sp[c]));
        pw[c] = 1.f + 4.f / (1.f + expf(-pp[c]));
    }
}

__global__ void cvt_bf16_kernel(const float* __restrict__ s, __hip_bfloat16* __restrict__ d,
                                long long n) {
    long long i = ((long long)blockIdx.x*256 + threadIdx.x)*4;
    if (i < n) {
        float4 v = *(const float4*)(s + i);
        union { __hip_bfloat16 h[4]; uint2 u; } t;
        t.h[0] = __float2bfloat16(v.x);
        t.h[1] = __float2bfloat16(v.y);
        t.h[2] = __float2bfloat16(v.z);
        t.h[3] = __float2bfloat16(v.w);
        *(uint2*)(d + i) = t.u;
    }
}

// src R x C fp32 -> dst C x R bf16
__global__ __launch_bounds__(256) void transpose_cvt(const float* __restrict__ s,
        __hip_bfloat16* __restrict__ d, int R, int Cc) {
    __shared__ float t[32][33];
    int c0 = blockIdx.x*32, r0 = blockIdx.y*32;
    int tx = threadIdx.x & 31, ty = threadIdx.x >> 5;
#pragma unroll
    for (int i = 0; i < 32; i += 8)
        t[ty+i][tx] = s[(long long)(r0+ty+i)*Cc + c0+tx];
    __syncthreads();
#pragma unroll
    for (int i = 0; i < 32; i += 8)
        d[(long long)(c0+ty+i)*R + r0+tx] = __float2bfloat16(t[tx][ty+i]);
}

// ---------------- 128x128 bf16 MFMA GEMM ----------------
// C = A(MxK) @ Bt^T where Bt is N x K (pre-transposed), both bf16, fp32 accum.
// EPI 0 (QG): col<512 -> o0[row*512+col] = acc/p0[col]; else o1 bf16(acc) (g)
// EPI 1 (KV): col<512 -> o0 = (acc + p1[n*512+col])/p0[col]; else o1 bf16(acc) (v)
// EPI 2 (FF1): o1[row*ldo+col] = bf16(relu(acc + p0[col]))
// EPI 3 (FF2): o0[row*512+col] += acc + p0[col]   (residual already in o0)
template<int EPI>
__global__ __launch_bounds__(256) void gemm_mfma(
    const __hip_bfloat16* __restrict__ A, int lda,
    const __hip_bfloat16* __restrict__ Bt, int ldbt,
    int Ktot, int ldo,
    float* __restrict__ o0, __hip_bfloat16* __restrict__ o1,
    const float* __restrict__ p0, const float* __restrict__ p1)
{
    __shared__ __hip_bfloat16 As[128*32];
    __shared__ __hip_bfloat16 Bs[128*32];
    const int tid = threadIdx.x;
    const int lane = tid & 63, w = tid >> 6;
    const int wm = w >> 1, wn = w & 1;
    const int quad = lane >> 4, l16 = lane & 15;
    const int m0 = blockIdx.y * 128, n0 = blockIdx.x * 128;
    const int srow = lane >> 2;          // 0..15
    const int scol = (lane & 3) * 8;     // bf16 elements

    ffrag acc[4][4];
#pragma unroll
    for (int i = 0; i < 4; ++i)
#pragma unroll
        for (int j = 0; j < 4; ++j)
#pragma unroll
            for (int r = 0; r < 4; ++r) acc[i][j][r] = 0.f;

    for (int k0 = 0; k0 < Ktot; k0 += 32) {
        __syncthreads();
#pragma unroll
        for (int t = 0; t < 2; ++t) {
            const __hip_bfloat16* gp = A + (long long)(m0 + t*64 + w*16 + srow)*lda + k0 + scol;
            gld_lds16(gp, As + (t*64 + w*16)*32);
        }
#pragma unroll
        for (int t = 0; t < 2; ++t) {
            const __hip_bfloat16* gp = Bt + (long long)(n0 + t*64 + w*16 + srow)*ldbt + k0 + scol;
            gld_lds16(gp, Bs + (t*64 + w*16)*32);
        }
        __syncthreads();
        bfrag af[4], bf[4];
#pragma unroll
        for (int i = 0; i < 4; ++i)
            af[i] = *(const bfrag*)(As + (wm*64 + i*16 + l16)*32 + quad*8);
#pragma unroll
        for (int j = 0; j < 4; ++j)
            bf[j] = *(const bfrag*)(Bs + (wn*64 + j*16 + l16)*32 + quad*8);
#pragma unroll
        for (int i = 0; i < 4; ++i)
#pragma unroll
            for (int j = 0; j < 4; ++j)
                acc[i][j] = __builtin_amdgcn_mfma_f32_16x16x32_bf16(af[i], bf[j], acc[i][j], 0, 0, 0);
    }

#pragma unroll
    for (int i = 0; i < 4; ++i) {
        int rbase = m0 + wm*64 + i*16 + quad*4;
#pragma unroll
        for (int r = 0; r < 4; ++r) {
            long long grow = rbase + r;
            int nmod = 0;
            if constexpr (EPI == 1) nmod = (int)(grow % N_);
#pragma unroll
            for (int j = 0; j < 4; ++j) {
                int gcol = n0 + wn*64 + j*16 + l16;
                float v = acc[i][j][r];
                if constexpr (EPI == 0) {
                    if (gcol < 512) o0[grow*512 + gcol] = v / p0[gcol];
                    else o1[grow*512 + gcol - 512] = __float2bfloat16(v);
                } else if constexpr (EPI == 1) {
                    if (gcol < 512) o0[grow*512 + gcol] = (v + p1[(long long)nmod*512 + gcol]) / p0[gcol];
                    else o1[grow*512 + gcol - 512] = __float2bfloat16(v);
                } else if constexpr (EPI == 2) {
                    o1[grow*(long long)ldo + gcol] = __float2bfloat16(fmaxf(v + p0[gcol], 0.f));
                } else {
                    o0[grow*512 + gcol] = o0[grow*512 + gcol] + v + p0[gcol];
                }
            }
        }
    }
}

// kvagg[zb][d2][m] = sum_n kc[n,d2]*v[n,m]; km[zb][d2] = sum_n kc[n,d2]. 16 n per barrier round.
__global__ __launch_bounds__(256) void kvagg_kernel(const float* __restrict__ kraw,
                                                    const __hip_bfloat16* __restrict__ vb,
                                                    const float* __restrict__ pw,
                                                    float* __restrict__ km,
                                                    float* __restrict__ kvagg)
{
    int zb = blockIdx.x;            // b*8+h
    int b = zb >> 3, h = zb & 7;
    int chunk = blockIdx.y;         // 16 chunks x 196 n
    int tid = threadIdx.x;
    __shared__ float kcl[16][128];
    __shared__ float vl[16][64];
    float acc[32];
#pragma unroll
    for (int j = 0; j < 32; ++j) acc[j] = 0.f;
    float kmacc = 0.f;
    const int dd = tid & 63;
    const float p = pw[h*64 + dd];
    const int m = tid & 63, dq = tid >> 6;
    for (int r = 0; r < 13; ++r) {
        int n0 = chunk*196 + r*16;
        int cnt = (r < 12) ? 16 : 4;
        __syncthreads();
#pragma unroll
        for (int i = 0; i < 4; ++i) {
            int nl = (tid >> 6) + i*4;
            if (nl < cnt) {
                long long rb = ((long long)(b*N_ + n0 + nl))*512 + h*64 + dd;
                float kv_ = kraw[rb];
                kcl[nl][dd]      = kv_ > 0.f ? powf(kv_, p) : 0.f;
                kcl[nl][64 + dd] = kv_ < 0.f ? powf(-kv_, p) : 0.f;
                vl[nl][dd] = __bfloat162float(vb[rb]);
            }
        }
        __syncthreads();
        for (int nl = 0; nl < cnt; ++nl) {
            float vm = vl[nl][m];
            const float4* kp = (const float4*)&kcl[nl][dq*32];
#pragma unroll
            for (int j4 = 0; j4 < 8; ++j4) {
                float4 kk = kp[j4];
                acc[j4*4+0] = fmaf(kk.x, vm, acc[j4*4+0]);
                acc[j4*4+1] = fmaf(kk.y, vm, acc[j4*4+1]);
                acc[j4*4+2] = fmaf(kk.z, vm, acc[j4*4+2]);
                acc[j4*4+3] = fmaf(kk.w, vm, acc[j4*4+3]);
            }
        }
        if (tid < 128) {
            for (int nl = 0; nl < cnt; ++nl) kmacc += kcl[nl][tid];
        }
    }
#pragma unroll
    for (int j = 0; j < 32; ++j)
        atomicAdd(&kvagg[(long long)zb*8192 + (dq*32 + j)*64 + m], acc[j]);
    if (tid < 128) atomicAdd(&km[zb*128 + tid], kmacc);
}

// Bmat[z][d][j] = kvagg[z][ j<32 ? d : (d+64)%128 ][j] / N
__global__ void bmat_kernel(const float* __restrict__ kvagg, float* __restrict__ bmat) {
    int idx = blockIdx.x * 256 + threadIdx.x;     // < 64*8192
    int z = idx >> 13, r = idx & 8191;
    int d = r >> 6, j = r & 63;
    int sd = (j < 32) ? d : ((d + 64) & 127);
    bmat[idx] = kvagg[((long long)z << 13) + (sd << 6) + j] * (1.0f / (float)N_);
}

// z1/z2 per (b,h,n)
__global__ __launch_bounds__(256) void z_kernel(const float* __restrict__ qraw,
                                                const float* __restrict__ pw,
                                                const float* __restrict__ km,
                                                float* __restrict__ z1, float* __restrict__ z2)
{
    int zb = blockIdx.x;
    int b = zb >> 3, h = zb & 7;
    int n0 = blockIdx.y * 64;
    __shared__ float kmn[128];
    __shared__ float q[64][129];
    int tid = threadIdx.x;
    if (tid < 128) kmn[tid] = km[zb*128 + tid] * (1.0f / (float)N_);
    for (int i = tid; i < 64*64; i += 256) {
        int nl = i >> 6, d = i & 63;
        float qv = qraw[((long long)(b*N_ + n0 + nl))*512 + h*64 + d];
        float p = pw[h*64 + d];
        q[nl][d]      = safe_pow(qv, p);
        q[nl][d + 64] = safe_pow(-qv, p);
    }
    __syncthreads();
    int nl = tid >> 2, qtr = tid & 3;
    float p1 = 0.f, p2 = 0.f;
    int d0 = qtr * 32;
    for (int d = d0; d < d0 + 32; ++d) {
        p1 = fmaf(q[nl][d], kmn[d], p1);
        p2 = fmaf(q[nl][(d + 64) & 127], kmn[d], p2);
    }
    p1 += __shfl_xor(p1, 1); p1 += __shfl_xor(p1, 2);
    p2 += __shfl_xor(p2, 1); p2 += __shfl_xor(p2, 2);
    if (qtr == 0) {
        int n = n0 + nl;
        z1[(long long)zb*N_ + n] = 1.0f / (p1 + 1e-6f);
        z2[(long long)zb*N_ + n] = 1.0f / (p2 + 1e-6f);
    }
}

// attn = (qs @ bmat) * z -> bf16; qs powers computed on the fly from qraw
__global__ __launch_bounds__(256) void attn_gemm(const float* __restrict__ qraw,
                                                 const float* __restrict__ bmat,
                                                 const float* __restrict__ pw,
                                                 const float* __restrict__ z1,
                                                 const float* __restrict__ z2,
                                                 __hip_bfloat16* __restrict__ attnb)
{
    int zb = blockIdx.y;
    int b = zb >> 3, h = zb & 7;
    const float* Ab = qraw + (long long)b*N_*512 + h*64;
    const float* Bb = bmat + (long long)zb*8192;
    const float* pwh = pw + h*64;
    const int m0 = blockIdx.x * 64;
    const int tid = threadIdx.x;
    const int ty = tid >> 4, tx = tid & 15;
    const int arow = tid >> 2, acol = (tid & 3) * 4;
    const int brow = tid >> 4, bcol = (tid & 15) * 4;

    __shared__ float As[16][68];
    __shared__ float Bs[16][68];
    float acc[4][4] = {};

    for (int k0 = 0; k0 < 128; k0 += 16) {
        int kk = k0 + acol;
        int kb = kk & 63;
        float4 raw = *(const float4*)(Ab + (long long)(m0 + arow)*512 + kb);
        float sgn = (kk >= 64) ? -1.f : 1.f;
        float4 av;
        av.x = safe_pow(sgn*raw.x, pwh[kb+0]);
        av.y = safe_pow(sgn*raw.y, pwh[kb+1]);
        av.z = safe_pow(sgn*raw.z, pwh[kb+2]);
        av.w = safe_pow(sgn*raw.w, pwh[kb+3]);
        float4 bv = *(const float4*)(Bb + (long long)(k0 + brow)*64 + bcol);
        __syncthreads();
        As[acol+0][arow] = av.x;
        As[acol+1][arow] = av.y;
        As[acol+2][arow] = av.z;
        As[acol+3][arow] = av.w;
        *(float4*)&Bs[brow][bcol] = bv;
        __syncthreads();
#pragma unroll
        for (int kx = 0; kx < 16; ++kx) {
            float4 a4 = *(const float4*)&As[kx][ty*4];
            float4 b4 = *(const float4*)&Bs[kx][tx*4];
            float ar[4] = {a4.x, a4.y, a4.z, a4.w};
            float br[4] = {b4.x, b4.y, b4.z, b4.w};
#pragma unroll
            for (int i = 0; i < 4; ++i)
#pragma unroll
                for (int j = 0; j < 4; ++j)
                    acc[i][j] = fmaf(ar[i], br[j], acc[i][j]);
        }
    }
#pragma unroll
    for (int i = 0; i < 4; ++i) {
        int row = m0 + ty*4 + i;
#pragma unroll
        for (int j = 0; j < 4; ++j) {
            int col = tx*4 + j;
            float zz = ((col < 32) ? z1 : z2)[(long long)zb*N_ + row];
            attnb[((long long)(b*N_ + row))*512 + h*64 + col] = __float2bfloat16(acc[i][j] * zz);
        }
    }
}

// x2 = (attn + conv(v)+b)*g -> out (f32) and gx2 (bf16, in-place over g)
// LDS-tiled depthwise 5x5: block = (b, head, 4-row y-strip, 28-col x-strip).
// Patch 8y x 32x x 64c bf16 (32 KB), each v read once from HBM/L2; 25 taps hit LDS.
__global__ __launch_bounds__(256) void conv_combine(
    const __hip_bfloat16* __restrict__ vb, const float* __restrict__ dwc_w,
    const float* __restrict__ dwc_b, const __hip_bfloat16* __restrict__ attnb,
    __hip_bfloat16* __restrict__ gx2, float* __restrict__ out)
{
    __shared__ __hip_bfloat16 patch[8][32][64];
    __shared__ float wsh[1600];
    __shared__ float bsh[64];
    const int tid = threadIdx.x;
    const int zb = blockIdx.z;           // b*8+h
    const int b = zb >> 3, h = zb & 7;
    const int y0 = blockIdx.y * 4;       // 14 y-strips
    const int x0 = blockIdx.x * 28;      // 2 x-strips

    for (int i = tid; i < 1600; i += 256) wsh[i] = dwc_w[i];
    if (tid < 64) bsh[tid] = dwc_b[tid];

    // stage patch: 4096 uint2 chunks (4 bf16 each), coalesced along c; halo -> 0
    for (int ci = tid; ci < 4096; ci += 256) {
        int c4 = ci & 15;                // 16 chunks of 4 ch
        int xs = (ci >> 4) & 31;
        int yy = ci >> 9;                // 0..7
        int gy = y0 - 2 + yy, gx = x0 - 2 + xs;
        uint2 val; val.x = 0u; val.y = 0u;
        if ((unsigned)gy < 56u && (unsigned)gx < 56u) {
            long long n = gy*56 + gx;
            val = *(const uint2*)(vb + ((long long)b*N_ + n)*512 + h*64 + c4*4);
        }
        *(uint2*)&patch[yy][xs][c4*4] = val;
    }
    __syncthreads();

    const int c = tid & 63;              // channel within head (= filter index)
    const int xg = tid >> 6;             // 0..3, 7 x each
    float wr[25];
#pragma unroll
    for (int t = 0; t < 25; ++t) wr[t] = wsh[c*25 + t];
    const float bias = bsh[c];
    const int C = h*64 + c;

    for (int yl = 0; yl < 4; ++yl) {
        for (int xi7 = 0; xi7 < 7; ++xi7) {
            int xi = xg*7 + xi7;
            float sum = bias;
#pragma unroll
            for (int ky = 0; ky < 5; ++ky)
#pragma unroll
                for (int kx = 0; kx < 5; ++kx)
                    sum = fmaf(wr[ky*5+kx],
                               __bfloat162float(patch[yl+ky][xi+kx][c]), sum);
            int n = (y0 + yl)*56 + x0 + xi;
            long long row = (long long)b*N_ + n;
            float attn = __bfloat162float(attnb[row*512 + C]);
            float g = __bfloat162float(gx2[row*512 + C]);
            float x2 = (attn + sum) * g;
            out[row*512 + C] = x2;
            gx2[row*512 + C] = __float2bfloat16(x2);
        }
    }
}

__global__ __launch_bounds__(256) void ln_kernel(float* __restrict__ y,
                                                 const float* __restrict__ g,
                                                 const float* __restrict__ bta)
{
    int wid = threadIdx.x >> 6, lane = threadIdx.x & 63;
    long long row = (long long)blockIdx.x*4 + wid;
    float v[8];
    float s = 0.f, s2 = 0.f;
#pragma unroll
    for (int i = 0; i < 8; ++i) {
        v[i] = y[row*512 + i*64 + lane];
        s += v[i];
        s2 = fmaf(v[i], v[i], s2);
    }
#pragma unroll
    for (int o = 32; o > 0; o >>= 1) { s += __shfl_xor(s, o); s2 += __shfl_xor(s2, o); }
    float mu = s * (1.f/512.f);
    float var = s2 * (1.f/512.f) - mu*mu;
    float rstd = rsqrtf(var + 1e-5f);
#pragma unroll
    for (int i = 0; i < 8; ++i) {
        int c = i*64 + lane;
        y[row*512 + c] = (v[i] - mu) * rstd * g[c] + bta[c];
    }
}

extern "C" void kernel_launch(void* const* d_in, const int* in_sizes, int n_in,
                              void* d_out, int out_size, void* d_ws, size_t ws_size,
                              hipStream_t stream)
{
    (void)in_sizes; (void)n_in; (void)out_size;
    if (ws_size < (size_t)WS_BYTES) return;  // fail loud (zero output), not crash

    const float* x       = (const float*)d_in[0];
    const float* Wqg     = (const float*)d_in[1];
    const float* Wkv     = (const float*)d_in[2];
    const float* pos     = (const float*)d_in[3];
    const float* scale_p = (const float*)d_in[4];
    const float* power_p = (const float*)d_in[5];
    const float* dwc_w   = (const float*)d_in[6];
    const float* dwc_b   = (const float*)d_in[7];
    const float* ln_g    = (const float*)d_in[8];
    const float* ln_b    = (const float*)d_in[9];
    const float* W1      = (const float*)d_in[10];
    const float* b1      = (const float*)d_in[11];
    const float* W2      = (const float*)d_in[12];
    const float* b2      = (const float*)d_in[13];
    float* out = (float*)d_out;
    char* ws   = (char*)d_ws;

    float* kraw  = (float*)(ws + OFF_KRAW);
    float* qraw  = (float*)(ws + OFF_QRAW);
    __hip_bfloat16* xb   = (__hip_bfloat16*)(ws + OFF_XB);
    __hip_bfloat16* vb   = (__hip_bfloat16*)(ws + OFF_VB);
    __hip_bfloat16* attnb= (__hip_bfloat16*)(ws + OFF_ATTN);
    __hip_bfloat16* gx2  = (__hip_bfloat16*)(ws + OFF_GX2);
    __hip_bfloat16* Wqgt = (__hip_bfloat16*)(ws + OFF_WQGT);
    __hip_bfloat16* Wkvt = (__hip_bfloat16*)(ws + OFF_WKVT);
    __hip_bfloat16* W1t  = (__hip_bfloat16*)(ws + OFF_W1T);
    __hip_bfloat16* W2t  = (__hip_bfloat16*)(ws + OFF_W2T);
    __hip_bfloat16* h1b  = (__hip_bfloat16*)(ws + OFF_H1B);
    float* km    = (float*)(ws + OFF_KM);
    float* kvagg = (float*)(ws + OFF_KVAGG);
    float* bmat  = (float*)(ws + OFF_BMAT);
    float* z1    = (float*)(ws + OFF_Z1);
    float* z2    = (float*)(ws + OFF_Z2);
    float* sc    = (float*)(ws + OFF_SC);
    float* pw    = (float*)(ws + OFF_PW);

    prep_params<<<2, 256, 0, stream>>>(scale_p, power_p, sc, pw);
    zero_kernel<<<(64*128 + 64*8192 + 255)/256, 256, 0, stream>>>(km, 64*128 + 64*8192);
    cvt_bf16_kernel<<<(int)(((long long)M_*512/4 + 255)/256), 256, 0, stream>>>(x, xb, (long long)M_*512);
    transpose_cvt<<<dim3(32, 16), 256, 0, stream>>>(Wqg, Wqgt, 512, 1024);
    transpose_cvt<<<dim3(32, 16), 256, 0, stream>>>(Wkv, Wkvt, 512, 1024);
    transpose_cvt<<<dim3(128, 16), 256, 0, stream>>>(W1, W1t, 512, 4096);
    transpose_cvt<<<dim3(16, 128), 256, 0, stream>>>(W2, W2t, 4096, 512);

    // qg = x@Wqg -> qraw f32 + g bf16
    gemm_mfma<0><<<dim3(8, 196), 256, 0, stream>>>(xb, 512, Wqgt, 512, 512, 0,
                                                   qraw, gx2, sc, nullptr);
    // kv = x@Wkv -> kraw f32 + v bf16
    gemm_mfma<1><<<dim3(8, 196), 256, 0, stream>>>(xb, 512, Wkvt, 512, 512, 0,
                                                   kraw, vb, sc, pos);

    kvagg_kernel<<<dim3(64, 16), 256, 0, stream>>>(kraw, vb, pw, km, kvagg);
    bmat_kernel<<<2048, 256, 0, stream>>>(kvagg, bmat);
    z_kernel<<<dim3(64, 49), 256, 0, stream>>>(qraw, pw, km, z1, z2);
    attn_gemm<<<dim3(49, 64), 256, 0, stream>>>(qraw, bmat, pw, z1, z2, attnb);

    conv_combine<<<dim3(2, 14, 64), 256, 0, stream>>>(vb, dwc_w, dwc_b, attnb, gx2, out);

    for (int c = 0; c < 2; ++c) {
        const __hip_bfloat16* x2c = gx2 + (long long)c*FFCHUNK*512;
        float* outc = out + (long long)c*FFCHUNK*512;
        gemm_mfma<2><<<dim3(32, FFCHUNK/128), 256, 0, stream>>>(
            x2c, 512, W1t, 512, 512, 4096, nullptr, h1b, b1, nullptr);
        gemm_mfma<3><<<dim3(4, FFCHUNK/128), 256, 0, stream>>>(
            h1b, 4096, W2t, 4096, 4096, 0, outc, nullptr, b2, nullptr);
    }

    ln_kernel<<<6272, 256, 0, stream>>>(out, ln_g, ln_b);
}